// Round 14
// baseline (275.852 us; speedup 1.0000x reference)
//
#include <hip/hip_runtime.h>
#include <hip/hip_bf16.h>

#define N_PTS 8192
#define KNN 8
#define GRID_DIM 32
#define NCELLS 32768
#define CELL_S 0.25f
#define GRID_LO (-4.0f)

typedef __attribute__((ext_vector_type(8))) short short8;
typedef __attribute__((ext_vector_type(4))) float float4v;
typedef unsigned long long u64;
typedef unsigned int u32;

// f32 -> bf16 round-to-nearest-even (finite inputs only)
static __device__ __forceinline__ short f2bf(float f) {
    unsigned u = __float_as_uint(f);
    unsigned r = (u + 0x7FFFu + ((u >> 16) & 1u)) >> 16;
    return (short)r;
}
static __device__ __forceinline__ float bf2f(short s) {
    return __uint_as_float(((unsigned)(unsigned short)s) << 16);
}

// monotone float -> u32 key (handles negative d' = |c|^2 - 2 q.c)
static __device__ __forceinline__ unsigned sortkey(float f) {
    unsigned u = __float_as_uint(f);
    return u ^ (((unsigned)((int)u >> 31)) | 0x80000000u);
}

static __device__ __forceinline__ void ins8(u64* best, u64 x) {
#pragma unroll
    for (int j = 0; j < 8; ++j) {
        const u64 lo = x < best[j] ? x : best[j];
        const u64 hi = x < best[j] ? best[j] : x;
        best[j] = lo; x = hi;
    }
}

// VGPR-pinned min update (r5 verified win 107->86 us). SESSION LAWS:
// only ONE query's 32-bucket state fits the ~44-VGPR budget (r7/r10);
// the 2-pass broadcast-LDS scan is the DS-issue bound (~86 us); every
// alternative fetch topology regressed (r2/r4/r6/r8/r9); relocate
// computation ORDER, not data (r12 vs r13: -30 us swing).
static __device__ __forceinline__ void vmin_acc(float& acc, float d) {
    asm("v_min_f32 %0, %0, %1" : "+v"(acc) : "v"(d));
}
static __device__ __forceinline__ void vsort2(float& a, float& x) {
    float lo, hi;
    asm("v_min_f32 %0, %2, %3\n\tv_max_f32 %1, %2, %3"
        : "=&v"(lo), "=v"(hi) : "v"(a), "v"(x));
    a = lo; x = hi;
}

static __device__ __forceinline__ int cell_coord(float v) {
    int c = (int)floorf((v - GRID_LO) * (1.0f / CELL_S));
    c = c < 0 ? 0 : c;
    c = c > GRID_DIM - 1 ? GRID_DIM - 1 : c;
    return c;
}
static __device__ __forceinline__ unsigned spread5(int v) {
    return (unsigned)((v & 1) | ((v & 2) << 2) | ((v & 4) << 4)
                    | ((v & 8) << 6) | ((v & 16) << 8));
}

// Async global->LDS staging, 16 B per lane (m97 recipe: compiler never
// auto-emits this; width=16 was the +67% step on the verified ladder).
static __device__ __forceinline__ void gload16(const short* gsrc, short* ldst) {
    __builtin_amdgcn_global_load_lds(
        (const __attribute__((address_space(1))) unsigned int*)gsrc,
        (__attribute__((address_space(3))) unsigned int*)ldst, 16, 0, 0);
}

// ---------------------------------------------------------------------------
// Dispatch 1: knn_partial (1024 blocks) + conversions (4096 blocks) + Morton
// histogram (64 blocks, hidden under the knn flood). BIT-IDENTICAL to r13
// (verified 267 us total, knn 86.8 us).
// ---------------------------------------------------------------------------
__global__ __launch_bounds__(256) void fused_knn_conv(const float* __restrict__ pos,
                                                      u64* __restrict__ partial,
                                                      const float* __restrict__ x,
                                                      const float* __restrict__ Wq,
                                                      const float* __restrict__ Wkv,
                                                      const float* __restrict__ Wout,
                                                      short* __restrict__ xb,
                                                      short* __restrict__ wqkvt,
                                                      short* __restrict__ woutt,
                                                      u32* __restrict__ cellCount,
                                                      unsigned short* __restrict__ cid)
{
    __shared__ __align__(16) char smem[16896];
    const int tid = threadIdx.x;

    if (blockIdx.x >= 5120) {
        // ================= Morton histogram (64 blocks) ===================
        const int i = (blockIdx.x - 5120) * 256 + tid;   // 0..16383
        const int b = i >> 13;
        const float px = pos[i * 3 + 0];
        const float py = pos[i * 3 + 1];
        const float pz = pos[i * 3 + 2];
        const unsigned m = spread5(cell_coord(px))
                         | (spread5(cell_coord(py)) << 1)
                         | (spread5(cell_coord(pz)) << 2);
        cid[i] = (unsigned short)m;
        atomicAdd(&cellCount[b * NCELLS + m], 1u);
        return;
    }

    const int g5 = blockIdx.x / 5;
    const int r5 = blockIdx.x % 5;

    if (r5 == 0) {
        // ================= KNN block (1024 total) =========================
        const int kb = g5;                       // 0..1023
        float4* cand = (float4*)smem;            // 512 x (x,y,z,|c|^2) = 8192 B
        unsigned short* buf = (unsigned short*)(smem + 8192);  // [256][17] u16

        const int p   = kb & 15;
        const int qg  = kb >> 4;
        const int batch = qg >> 5;
        const int q_in_b = (qg & 31) * 256 + tid;
        const float* bpos = pos + (long)batch * N_PTS * 3;

        if (tid < 128) {
            const float* src = bpos + (p * 512 + tid * 4) * 3;
            const float4 f0 = *(const float4*)(src);
            const float4 f1 = *(const float4*)(src + 4);
            const float4 f2 = *(const float4*)(src + 8);
            const int c0 = tid * 4;
            cand[c0 + 0] = make_float4(f0.x, f0.y, f0.z,
                                       fmaf(f0.x, f0.x, fmaf(f0.y, f0.y, f0.z * f0.z)));
            cand[c0 + 1] = make_float4(f0.w, f1.x, f1.y,
                                       fmaf(f0.w, f0.w, fmaf(f1.x, f1.x, f1.y * f1.y)));
            cand[c0 + 2] = make_float4(f1.z, f1.w, f2.x,
                                       fmaf(f1.z, f1.z, fmaf(f1.w, f1.w, f2.x * f2.x)));
            cand[c0 + 3] = make_float4(f2.y, f2.z, f2.w,
                                       fmaf(f2.y, f2.y, fmaf(f2.z, f2.z, f2.w * f2.w)));
        }
        __syncthreads();

        const float qx = bpos[q_in_b * 3 + 0];
        const float qy = bpos[q_in_b * 3 + 1];
        const float qz = bpos[q_in_b * 3 + 2];
        const float nqx = -2.0f * qx;
        const float nqy = -2.0f * qy;
        const float nqz = -2.0f * qz;

        float bmin[32];
#pragma unroll
        for (int j = 0; j < 32; ++j) bmin[j] = 3.0e38f;

        for (int base = 0; base < 512; base += 32) {
#pragma unroll
            for (int g = 0; g < 32; ++g) {
                const float4 c = cand[base + g];
                const float d = fmaf(c.x, nqx, fmaf(c.y, nqy, fmaf(c.z, nqz, c.w)));
                vmin_acc(bmin[g], d);                // VGPR-pinned
            }
        }

        float t8[8];
#pragma unroll
        for (int j = 0; j < 8; ++j) t8[j] = 3.0e38f;
#pragma unroll
        for (int i = 0; i < 32; ++i) {
            float x_ = bmin[i];
#pragma unroll
            for (int j = 0; j < 8; ++j)
                vsort2(t8[j], x_);                   // VGPR-pinned
        }
        const float t = t8[7];

        int cnt = 0;
        for (int base = 0; base < 512; base += 32) {
#pragma unroll
            for (int g = 0; g < 32; ++g) {
                const float4 c = cand[base + g];
                const float d = fmaf(c.x, nqx, fmaf(c.y, nqy, fmaf(c.z, nqz, c.w)));
                if (d <= t) {
                    buf[tid * 17 + (cnt < 16 ? cnt : 16)] = (unsigned short)(base + g);
                    ++cnt;
                }
            }
        }

        u64 best[8];
#pragma unroll
        for (int j = 0; j < 8; ++j) best[j] = ~0ULL;

        if (cnt <= 16) {
            for (int u = 0; u < cnt; ++u) {
                const int i = buf[tid * 17 + u];
                const float4 c = cand[i];
                const float d = fmaf(c.x, nqx, fmaf(c.y, nqy, fmaf(c.z, nqz, c.w)));
                ins8(best, ((u64)sortkey(d) << 32) | (unsigned)(p * 512 + i));
            }
        } else {
            for (int i = 0; i < 512; ++i) {     // statistically-never fallback
                const float4 c = cand[i];
                const float d = fmaf(c.x, nqx, fmaf(c.y, nqy, fmaf(c.z, nqz, c.w)));
                const u64 x_ = ((u64)sortkey(d) << 32) | (unsigned)(p * 512 + i);
                if (x_ < best[7]) ins8(best, x_);
            }
        }

        const long qglob = (long)batch * N_PTS + q_in_b;
#pragma unroll
        for (int j = 0; j < 8; ++j)
            partial[(long)(p * 8 + j) * 16384 + qglob] = best[j];   // coalesced

    } else {
        // ================= conv block (4096 total, LDS-unused) ============
        const int bid = g5 * 4 + (r5 - 1);      // 0..4095
        if (bid < 2048) {
            const int i = bid * 256 + tid;
            const float4 a = ((const float4*)x)[i * 2];
            const float4 b = ((const float4*)x)[i * 2 + 1];
            short8 w = {f2bf(a.x), f2bf(a.y), f2bf(a.z), f2bf(a.w),
                        f2bf(b.x), f2bf(b.y), f2bf(b.z), f2bf(b.w)};
            ((short8*)xb)[i] = w;
        } else if (bid < 2560) {
            const int o = (bid - 2048) * 256 + tid;      // n*256+k, n<512
            const int n = o >> 8, k = o & 255;
            wqkvt[o] = f2bf(Wq[(long)k * 512 + n]);
        } else if (bid < 3584) {
            const int o = (bid - 2560) * 256 + tid;      // n*256+k, n<1024
            const int n = o >> 8, k = o & 255;
            wqkvt[131072 + o] = f2bf(Wkv[(long)k * 1024 + n]);
        } else {
            const int o = (bid - 3584) * 256 + tid;      // n*512+k, n<256
            const int n = o >> 9, k = o & 511;
            woutt[o] = f2bf(Wout[(long)k * 256 + n]);
        }
    }
}

// ---------------------------------------------------------------------------
// Dispatch 2: q/kv GEMM (1536 blocks) + knn_merge (64 blocks) + Morton scan
// (2 blocks, hidden). Round 14: GEMM staging switched to async
// global_load_lds width=16 (m97 recipe) with a k-plane linear LDS layout:
// plane p (16 B = 8 k-shorts) x 128 rows; segment seg = wave*2+s stages
// rows (seg&1)*64+lane of plane seg>>1 at linear byte base seg*1024
// (wave-uniform dest + per-lane source -- rule-21 compliant). Fragment
// read As[quad*1024 + row*8] has starting banks 4*(row%8): 8 starts x
// width 4 = full 32-bank coverage, 2 rows/bank -- same free conflict
// profile as the old padded [128][40]. Per-lane k-windows identical to
// the old layout => MFMA inputs bit-identical.
// ---------------------------------------------------------------------------
__global__ __launch_bounds__(256) void fused_gemm_merge(const short* __restrict__ A,
                                                        const short* __restrict__ Bt,
                                                        short* __restrict__ qall,
                                                        short* __restrict__ kvall,
                                                        const u64* __restrict__ partial,
                                                        int* __restrict__ idxo,
                                                        const u32* __restrict__ cellCount,
                                                        u32* __restrict__ cellStart)
{
    __shared__ short As[4096];                   // 4 planes x 128 rows x 16 B
    __shared__ short Bs[4096];

    const int tid = threadIdx.x;

    if (blockIdx.x >= 1600) {
        // ================= scan block (2 total) ===========================
        u32* psum = (u32*)As;                    // reuse LDS (1 KB of 16 KB)
        const int b = blockIdx.x - 1600;
        const u32* cnt = cellCount + b * NCELLS;
        u32* st = cellStart + b * (NCELLS + 1);

        u32 sum = 0;
        for (int j = 0; j < 128; ++j) sum += cnt[tid * 128 + j];
        psum[tid] = sum;
        __syncthreads();
        if (tid == 0) {
            u32 a = 0;
            for (int i = 0; i < 256; ++i) { const u32 t = psum[i]; psum[i] = a; a += t; }
        }
        __syncthreads();
        u32 run = psum[tid];
        for (int j = 0; j < 128; ++j) {
            st[tid * 128 + j] = run;
            run += cnt[tid * 128 + j];
        }
        if (tid == 255) st[NCELLS] = run;        // == 8192
        return;
    }

    if (blockIdx.x < 64) {
        // ================= merge block (zero LDS) =========================
        const int q = blockIdx.x * 256 + tid;
        u64 best[8];
#pragma unroll
        for (int j = 0; j < 8; ++j) best[j] = ~0ULL;
        for (int s = 0; s < 128; ++s) {
            u64 x = partial[(long)s * 16384 + q];
            if (x < best[7]) ins8(best, x);
        }
#pragma unroll
        for (int j = 0; j < 8; ++j)
            idxo[(long)q * 8 + j] = (int)(best[j] & 0xFFFFFFFFu);
        return;
    }

    // ================= GEMM block (1536 total) ============================
    const int id = blockIdx.x - 64;
    const int bx = id % 12;
    const int by = id / 12;

    const int lane = tid & 63;
    const int wv   = tid >> 6;
    const int quad = lane >> 4;
    const int l15  = lane & 15;
    const int m0 = by * 128;
    const int n0 = bx * 128;
    const int mh = (wv & 1) * 64, nh = (wv >> 1) * 64;
    const int Kd = 256;

    float4v acc[4][4];
#pragma unroll
    for (int i = 0; i < 4; ++i)
#pragma unroll
        for (int j = 0; j < 4; ++j) acc[i][j] = (float4v)(0.f);

    for (int k0 = 0; k0 < Kd; k0 += 32) {
#pragma unroll
        for (int s = 0; s < 2; ++s) {
            const int seg  = wv * 2 + s;                 // 0..7
            const int row  = ((seg & 1) << 6) + lane;    // per-lane source row
            const int koff = k0 + (seg >> 1) * 8;        // plane k-window
            gload16(A  + (long)(m0 + row) * Kd + koff, &As[seg * 512]);
            gload16(Bt + (long)(n0 + row) * Kd + koff, &Bs[seg * 512]);
        }
        __syncthreads();                                 // drains vmcnt + barrier

        short8 af[4], bfv[4];
#pragma unroll
        for (int i = 0; i < 4; ++i)
            af[i] = *(const short8*)&As[quad * 1024 + (mh + i * 16 + l15) * 8];
#pragma unroll
        for (int j = 0; j < 4; ++j)
            bfv[j] = *(const short8*)&Bs[quad * 1024 + (nh + j * 16 + l15) * 8];
#pragma unroll
        for (int i = 0; i < 4; ++i)
#pragma unroll
            for (int j = 0; j < 4; ++j)
                acc[i][j] = __builtin_amdgcn_mfma_f32_16x16x32_bf16(af[i], bfv[j], acc[i][j], 0, 0, 0);
        __syncthreads();
    }

    short* Cb;
    int stride, cb;
    if (n0 < 512) { Cb = qall;  stride = 512;  cb = n0; }
    else          { Cb = kvall; stride = 1024; cb = n0 - 512; }

#pragma unroll
    for (int i = 0; i < 4; ++i)
#pragma unroll
        for (int j = 0; j < 4; ++j) {
            const int col = cb + nh + j * 16 + l15;
#pragma unroll
            for (int r = 0; r < 4; ++r) {
                const int row = m0 + mh + i * 16 + quad * 4 + r;
                Cb[(long)row * stride + col] = f2bf(acc[i][j][r]);
            }
        }
}

// ---------------------------------------------------------------------------
// Dispatch 3: scatter -- builds rowmap[sorted] = original global group index.
// Index permutation only; no data moves (r12 lesson).
// ---------------------------------------------------------------------------
__global__ __launch_bounds__(256) void scatter_kernel(const unsigned short* __restrict__ cid,
                                                      const u32* __restrict__ cellStart,
                                                      u32* __restrict__ cellOff,
                                                      int* __restrict__ rowmap)
{
    const int i = blockIdx.x * 256 + threadIdx.x;    // original global 0..16383
    const int b = i >> 13;
    const int c = cid[i];
    const u32 dst = cellStart[b * (NCELLS + 1) + c] + atomicAdd(&cellOff[b * NCELLS + c], 1u);
    rowmap[b * N_PTS + dst] = i;
}

// ---------------------------------------------------------------------------
// Dispatch 4: fused KNN attention, Morton processing order + XCD-chunked
// swizzle (r13 win: spatially-adjacent queries share kv rows -> L2-hot
// gathers). Outputs bit-identical to r11 (order-only change).
// ---------------------------------------------------------------------------
__global__ __launch_bounds__(256) void attn_kernel(const short* qall,
                                                   const short* __restrict__ kvall,
                                                   const int* __restrict__ idxp,
                                                   const int* __restrict__ order,
                                                   short* outp)
{
    __shared__ float attn_s[4][8][8];
    const int wave = threadIdx.x >> 6;
    const int lane = threadIdx.x & 63;
    // XCD-chunked swizzle: XCD k processes sorted blocks [k*512, (k+1)*512)
    const int sbid = ((blockIdx.x & 7) << 9) | (blockIdx.x >> 3);
    const int g = order[sbid * 4 + wave];            // original global group
    const int b = g >> 13;
    const int* myidx = idxp + (long)g * 8;

    {
        const int h = lane >> 3;
        const int k = lane & 7;
        const int j = myidx[k];
        const short8* qrow = (const short8*)(qall + (long)g * 512 + h * 64);
        const short8* krow = (const short8*)(kvall + ((long)(b * N_PTS + j)) * 1024 + h * 64);

        float dot = 0.f;
#pragma unroll
        for (int c = 0; c < 8; ++c) {
            const short8 qv = qrow[c];
            const short8 kv = krow[c];
#pragma unroll
            for (int e = 0; e < 8; ++e)
                dot = fmaf(bf2f(qv[e]), bf2f(kv[e]), dot);
        }
        dot *= 0.125f;

        float m = dot;
#pragma unroll
        for (int off = 1; off < 8; off <<= 1)
            m = fmaxf(m, __shfl_xor(m, off, 8));
        const float e = __expf(dot - m);
        float ssum = e;
#pragma unroll
        for (int off = 1; off < 8; off <<= 1)
            ssum += __shfl_xor(ssum, off, 8);
        attn_s[wave][h][k] = e / ssum;
    }
    __syncthreads();                      // drains q reads before aliased writes

    const int d8 = lane * 8;
    const int h2 = lane >> 3;
    float o[8] = {0.f, 0.f, 0.f, 0.f, 0.f, 0.f, 0.f, 0.f};
#pragma unroll
    for (int kk = 0; kk < 8; ++kk) {
        const int jj = myidx[kk];
        const float w = attn_s[wave][h2][kk];
        const short8 v = *(const short8*)(kvall + ((long)(b * N_PTS + jj)) * 1024 + 512 + d8);
#pragma unroll
        for (int e = 0; e < 8; ++e)
            o[e] = fmaf(w, bf2f(v[e]), o[e]);
    }
    short8 ov = {f2bf(o[0]), f2bf(o[1]), f2bf(o[2]), f2bf(o[3]),
                 f2bf(o[4]), f2bf(o[5]), f2bf(o[6]), f2bf(o[7])};
    *(short8*)(outp + (long)g * 512 + d8) = ov;
}

// ---------------------------------------------------------------------------
// Dispatch 5: out-projection GEMM, same gload_lds k-plane staging (Kd=512).
// ---------------------------------------------------------------------------
__global__ __launch_bounds__(256) void gemm_out(const short* __restrict__ A,
                                                const short* __restrict__ Bt,
                                                const float* __restrict__ bias,
                                                float* __restrict__ C,
                                                int N, int Kd)
{
    __shared__ short As[4096];
    __shared__ short Bs[4096];

    const int tid  = threadIdx.x;
    const int lane = tid & 63;
    const int wv   = tid >> 6;
    const int quad = lane >> 4;
    const int l15  = lane & 15;
    const int m0 = blockIdx.y * 128;
    const int n0 = blockIdx.x * 128;
    const int mh = (wv & 1) * 64, nh = (wv >> 1) * 64;

    float4v acc[4][4];
#pragma unroll
    for (int i = 0; i < 4; ++i)
#pragma unroll
        for (int j = 0; j < 4; ++j) acc[i][j] = (float4v)(0.f);

    for (int k0 = 0; k0 < Kd; k0 += 32) {
#pragma unroll
        for (int s = 0; s < 2; ++s) {
            const int seg  = wv * 2 + s;
            const int row  = ((seg & 1) << 6) + lane;
            const int koff = k0 + (seg >> 1) * 8;
            gload16(A  + (long)(m0 + row) * Kd + koff, &As[seg * 512]);
            gload16(Bt + (long)(n0 + row) * Kd + koff, &Bs[seg * 512]);
        }
        __syncthreads();

        short8 af[4], bfv[4];
#pragma unroll
        for (int i = 0; i < 4; ++i)
            af[i] = *(const short8*)&As[quad * 1024 + (mh + i * 16 + l15) * 8];
#pragma unroll
        for (int j = 0; j < 4; ++j)
            bfv[j] = *(const short8*)&Bs[quad * 1024 + (nh + j * 16 + l15) * 8];
#pragma unroll
        for (int i = 0; i < 4; ++i)
#pragma unroll
            for (int j = 0; j < 4; ++j)
                acc[i][j] = __builtin_amdgcn_mfma_f32_16x16x32_bf16(af[i], bfv[j], acc[i][j], 0, 0, 0);
        __syncthreads();
    }

#pragma unroll
    for (int i = 0; i < 4; ++i)
#pragma unroll
        for (int j = 0; j < 4; ++j) {
            const int col = n0 + nh + j * 16 + l15;
            const float bb = bias[col];
#pragma unroll
            for (int r = 0; r < 4; ++r) {
                const int row = m0 + mh + i * 16 + quad * 4 + r;
                C[(long)row * N + col] = acc[i][j][r] + bb;
            }
        }
}

// ---------------------------------------------------------------------------
extern "C" void kernel_launch(void* const* d_in, const int* in_sizes, int n_in,
                              void* d_out, int out_size, void* d_ws, size_t ws_size,
                              hipStream_t stream)
{
    const float* x    = (const float*)d_in[0];  // [2,8192,256]
    const float* pos  = (const float*)d_in[1];  // [2,8192,3]
    const float* Wq   = (const float*)d_in[2];  // [256,512]
    const float* Wkv  = (const float*)d_in[3];  // [256,1024]
    const float* Wout = (const float*)d_in[4];  // [512,256]
    const float* bout = (const float*)d_in[5];  // [256]
    float* out = (float*)d_out;                 // [2,8192,256] f32

    const int M = 16384;

    // workspace layout:
    char* ws = (char*)d_ws;
    int*   idxp  = (int*)ws;                          ws += 1 << 19;             // 512 KB
    short* qall  = (short*)ws;                        ws += (long)M * 512 * 2;   // 16 MB
    short* kvall = (short*)ws;                        ws += (long)M * 1024 * 2;  // 32 MB
    short* xb    = (short*)ws;                        ws += (long)M * 256 * 2;   // 8 MB
    short* wqkvt = (short*)ws;                        ws += 1536 * 256 * 2;      // 768 KB
    short* woutt = (short*)ws;                        ws += 256 * 512 * 2;       // 256 KB
    u64*  partial = (u64*)ws;                         ws += (long)128 * 16384 * 8; // 16 MB
    u32*  cellCount = (u32*)ws;                       ws += 2L * NCELLS * 4;     // 256 KB
    u32*  cellOff   = (u32*)ws;                       ws += 2L * NCELLS * 4;     // 256 KB (contiguous w/ cellCount)
    u32*  cellStart = (u32*)ws;                       ws += 2L * (NCELLS + 1) * 4 + 56;
    unsigned short* cid = (unsigned short*)ws;        ws += (long)M * 2;         // 32 KB
    int*   rowmap = (int*)ws;                         ws += (long)M * 4;         // 64 KB

    hipMemsetAsync(cellCount, 0, 4L * NCELLS * 4, stream);   // count + off

    fused_knn_conv<<<5184, 256, 0, stream>>>(pos, partial, x, Wq, Wkv, Wout,
                                             xb, wqkvt, woutt, cellCount, cid);
    fused_gemm_merge<<<1602, 256, 0, stream>>>(xb, wqkvt, qall, kvall, partial,
                                               idxp, cellCount, cellStart);
    scatter_kernel<<<64, 256, 0, stream>>>(cid, cellStart, cellOff, rowmap);
    attn_kernel<<<M / 4, 256, 0, stream>>>(qall, kvall, idxp, rowmap, qall);  // in-place
    gemm_out<<<dim3(2, 128), 256, 0, stream>>>(qall, woutt, bout, out, 256, 512);
}

// Round 15
// 265.167 us; speedup vs baseline: 1.0403x; 1.0403x over previous
//
#include <hip/hip_runtime.h>
#include <hip/hip_bf16.h>

#define N_PTS 8192
#define KNN 8
#define GRID_DIM 32
#define NCELLS 32768
#define CELL_S 0.25f
#define GRID_LO (-4.0f)

typedef __attribute__((ext_vector_type(8))) short short8;
typedef __attribute__((ext_vector_type(4))) float float4v;
typedef unsigned long long u64;
typedef unsigned int u32;

// f32 -> bf16 round-to-nearest-even (finite inputs only)
static __device__ __forceinline__ short f2bf(float f) {
    unsigned u = __float_as_uint(f);
    unsigned r = (u + 0x7FFFu + ((u >> 16) & 1u)) >> 16;
    return (short)r;
}
static __device__ __forceinline__ float bf2f(short s) {
    return __uint_as_float(((unsigned)(unsigned short)s) << 16);
}

// monotone float -> u32 key (handles negative d' = |c|^2 - 2 q.c)
static __device__ __forceinline__ unsigned sortkey(float f) {
    unsigned u = __float_as_uint(f);
    return u ^ (((unsigned)((int)u >> 31)) | 0x80000000u);
}

static __device__ __forceinline__ void ins8(u64* best, u64 x) {
#pragma unroll
    for (int j = 0; j < 8; ++j) {
        const u64 lo = x < best[j] ? x : best[j];
        const u64 hi = x < best[j] ? best[j] : x;
        best[j] = lo; x = hi;
    }
}

// VGPR-pinned min update (r5 verified win 107->86 us). SESSION LAWS:
// only ONE query's 32-bucket state fits the ~44-VGPR budget (r7/r10);
// the 2-pass broadcast-LDS scan is the DS-issue bound (~86 us); every
// alternative fetch topology regressed (r2/r4/r6/r8/r9); relocate
// computation ORDER, not data (r12 vs r13: -30 us swing); small-K GEMMs
// prefer simple VGPR-round-trip staging over global_load_lds (r14: -9 us).
static __device__ __forceinline__ void vmin_acc(float& acc, float d) {
    asm("v_min_f32 %0, %0, %1" : "+v"(acc) : "v"(d));
}
static __device__ __forceinline__ void vsort2(float& a, float& x) {
    float lo, hi;
    asm("v_min_f32 %0, %2, %3\n\tv_max_f32 %1, %2, %3"
        : "=&v"(lo), "=v"(hi) : "v"(a), "v"(x));
    a = lo; x = hi;
}

static __device__ __forceinline__ int cell_coord(float v) {
    int c = (int)floorf((v - GRID_LO) * (1.0f / CELL_S));
    c = c < 0 ? 0 : c;
    c = c > GRID_DIM - 1 ? GRID_DIM - 1 : c;
    return c;
}
static __device__ __forceinline__ unsigned spread5(int v) {
    return (unsigned)((v & 1) | ((v & 2) << 2) | ((v & 4) << 4)
                    | ((v & 8) << 6) | ((v & 16) << 8));
}

// ---------------------------------------------------------------------------
// Dispatch 1: knn_partial (1024 blocks) + conversions (4096 blocks) + Morton
// histogram (64 extra blocks, LDS-free, hidden under the knn flood).
// knn/conv parts BIT-IDENTICAL to r11 (verified; knn 86 us).
// ---------------------------------------------------------------------------
__global__ __launch_bounds__(256) void fused_knn_conv(const float* __restrict__ pos,
                                                      u64* __restrict__ partial,
                                                      const float* __restrict__ x,
                                                      const float* __restrict__ Wq,
                                                      const float* __restrict__ Wkv,
                                                      const float* __restrict__ Wout,
                                                      short* __restrict__ xb,
                                                      short* __restrict__ wqkvt,
                                                      short* __restrict__ woutt,
                                                      u32* __restrict__ cellCount,
                                                      unsigned short* __restrict__ cid)
{
    __shared__ __align__(16) char smem[16896];
    const int tid = threadIdx.x;

    if (blockIdx.x >= 5120) {
        // ================= Morton histogram (64 blocks) ===================
        const int i = (blockIdx.x - 5120) * 256 + tid;   // 0..16383
        const int b = i >> 13;
        const float px = pos[i * 3 + 0];
        const float py = pos[i * 3 + 1];
        const float pz = pos[i * 3 + 2];
        const unsigned m = spread5(cell_coord(px))
                         | (spread5(cell_coord(py)) << 1)
                         | (spread5(cell_coord(pz)) << 2);
        cid[i] = (unsigned short)m;
        atomicAdd(&cellCount[b * NCELLS + m], 1u);
        return;
    }

    const int g5 = blockIdx.x / 5;
    const int r5 = blockIdx.x % 5;

    if (r5 == 0) {
        // ================= KNN block (1024 total) =========================
        const int kb = g5;                       // 0..1023
        float4* cand = (float4*)smem;            // 512 x (x,y,z,|c|^2) = 8192 B
        unsigned short* buf = (unsigned short*)(smem + 8192);  // [256][17] u16

        const int p   = kb & 15;
        const int qg  = kb >> 4;
        const int batch = qg >> 5;
        const int q_in_b = (qg & 31) * 256 + tid;
        const float* bpos = pos + (long)batch * N_PTS * 3;

        if (tid < 128) {
            const float* src = bpos + (p * 512 + tid * 4) * 3;
            const float4 f0 = *(const float4*)(src);
            const float4 f1 = *(const float4*)(src + 4);
            const float4 f2 = *(const float4*)(src + 8);
            const int c0 = tid * 4;
            cand[c0 + 0] = make_float4(f0.x, f0.y, f0.z,
                                       fmaf(f0.x, f0.x, fmaf(f0.y, f0.y, f0.z * f0.z)));
            cand[c0 + 1] = make_float4(f0.w, f1.x, f1.y,
                                       fmaf(f0.w, f0.w, fmaf(f1.x, f1.x, f1.y * f1.y)));
            cand[c0 + 2] = make_float4(f1.z, f1.w, f2.x,
                                       fmaf(f1.z, f1.z, fmaf(f1.w, f1.w, f2.x * f2.x)));
            cand[c0 + 3] = make_float4(f2.y, f2.z, f2.w,
                                       fmaf(f2.y, f2.y, fmaf(f2.z, f2.z, f2.w * f2.w)));
        }
        __syncthreads();

        const float qx = bpos[q_in_b * 3 + 0];
        const float qy = bpos[q_in_b * 3 + 1];
        const float qz = bpos[q_in_b * 3 + 2];
        const float nqx = -2.0f * qx;
        const float nqy = -2.0f * qy;
        const float nqz = -2.0f * qz;

        float bmin[32];
#pragma unroll
        for (int j = 0; j < 32; ++j) bmin[j] = 3.0e38f;

        for (int base = 0; base < 512; base += 32) {
#pragma unroll
            for (int g = 0; g < 32; ++g) {
                const float4 c = cand[base + g];
                const float d = fmaf(c.x, nqx, fmaf(c.y, nqy, fmaf(c.z, nqz, c.w)));
                vmin_acc(bmin[g], d);                // VGPR-pinned
            }
        }

        float t8[8];
#pragma unroll
        for (int j = 0; j < 8; ++j) t8[j] = 3.0e38f;
#pragma unroll
        for (int i = 0; i < 32; ++i) {
            float x_ = bmin[i];
#pragma unroll
            for (int j = 0; j < 8; ++j)
                vsort2(t8[j], x_);                   // VGPR-pinned
        }
        const float t = t8[7];

        int cnt = 0;
        for (int base = 0; base < 512; base += 32) {
#pragma unroll
            for (int g = 0; g < 32; ++g) {
                const float4 c = cand[base + g];
                const float d = fmaf(c.x, nqx, fmaf(c.y, nqy, fmaf(c.z, nqz, c.w)));
                if (d <= t) {
                    buf[tid * 17 + (cnt < 16 ? cnt : 16)] = (unsigned short)(base + g);
                    ++cnt;
                }
            }
        }

        u64 best[8];
#pragma unroll
        for (int j = 0; j < 8; ++j) best[j] = ~0ULL;

        if (cnt <= 16) {
            for (int u = 0; u < cnt; ++u) {
                const int i = buf[tid * 17 + u];
                const float4 c = cand[i];
                const float d = fmaf(c.x, nqx, fmaf(c.y, nqy, fmaf(c.z, nqz, c.w)));
                ins8(best, ((u64)sortkey(d) << 32) | (unsigned)(p * 512 + i));
            }
        } else {
            for (int i = 0; i < 512; ++i) {     // statistically-never fallback
                const float4 c = cand[i];
                const float d = fmaf(c.x, nqx, fmaf(c.y, nqy, fmaf(c.z, nqz, c.w)));
                const u64 x_ = ((u64)sortkey(d) << 32) | (unsigned)(p * 512 + i);
                if (x_ < best[7]) ins8(best, x_);
            }
        }

        const long qglob = (long)batch * N_PTS + q_in_b;
#pragma unroll
        for (int j = 0; j < 8; ++j)
            partial[(long)(p * 8 + j) * 16384 + qglob] = best[j];   // coalesced

    } else {
        // ================= conv block (4096 total, LDS-unused) ============
        const int bid = g5 * 4 + (r5 - 1);      // 0..4095
        if (bid < 2048) {
            const int i = bid * 256 + tid;
            const float4 a = ((const float4*)x)[i * 2];
            const float4 b = ((const float4*)x)[i * 2 + 1];
            short8 w = {f2bf(a.x), f2bf(a.y), f2bf(a.z), f2bf(a.w),
                        f2bf(b.x), f2bf(b.y), f2bf(b.z), f2bf(b.w)};
            ((short8*)xb)[i] = w;
        } else if (bid < 2560) {
            const int o = (bid - 2048) * 256 + tid;      // n*256+k, n<512
            const int n = o >> 8, k = o & 255;
            wqkvt[o] = f2bf(Wq[(long)k * 512 + n]);
        } else if (bid < 3584) {
            const int o = (bid - 2560) * 256 + tid;      // n*256+k, n<1024
            const int n = o >> 8, k = o & 255;
            wqkvt[131072 + o] = f2bf(Wkv[(long)k * 1024 + n]);
        } else {
            const int o = (bid - 3584) * 256 + tid;      // n*512+k, n<256
            const int n = o >> 9, k = o & 511;
            woutt[o] = f2bf(Wout[(long)k * 256 + n]);
        }
    }
}

// ---------------------------------------------------------------------------
// Dispatch 2: q/kv GEMM (1536 blocks) + knn_merge (64 blocks) + Morton scan
// (2 extra blocks, hidden under the gemm flood). gemm/merge BIT-IDENTICAL
// to r11 (r14 lesson: gload_lds staging regressed these small-K GEMMs).
// ---------------------------------------------------------------------------
__global__ __launch_bounds__(256) void fused_gemm_merge(const short* __restrict__ A,
                                                        const short* __restrict__ Bt,
                                                        short* __restrict__ qall,
                                                        short* __restrict__ kvall,
                                                        const u64* __restrict__ partial,
                                                        int* __restrict__ idxo,
                                                        const u32* __restrict__ cellCount,
                                                        u32* __restrict__ cellStart)
{
    __shared__ short As[128][40];
    __shared__ short Bs[128][40];

    const int tid = threadIdx.x;

    if (blockIdx.x >= 1600) {
        // ================= scan block (2 total) ===========================
        u32* psum = (u32*)As;                    // reuse LDS (1 KB of 10 KB)
        const int b = blockIdx.x - 1600;
        const u32* cnt = cellCount + b * NCELLS;
        u32* st = cellStart + b * (NCELLS + 1);

        u32 sum = 0;
        for (int j = 0; j < 128; ++j) sum += cnt[tid * 128 + j];
        psum[tid] = sum;
        __syncthreads();
        if (tid == 0) {
            u32 a = 0;
            for (int i = 0; i < 256; ++i) { const u32 t = psum[i]; psum[i] = a; a += t; }
        }
        __syncthreads();
        u32 run = psum[tid];
        for (int j = 0; j < 128; ++j) {
            st[tid * 128 + j] = run;
            run += cnt[tid * 128 + j];
        }
        if (tid == 255) st[NCELLS] = run;        // == 8192
        return;
    }

    if (blockIdx.x < 64) {
        // ================= merge block (zero LDS) =========================
        const int q = blockIdx.x * 256 + tid;
        u64 best[8];
#pragma unroll
        for (int j = 0; j < 8; ++j) best[j] = ~0ULL;
        for (int s = 0; s < 128; ++s) {
            u64 x = partial[(long)s * 16384 + q];
            if (x < best[7]) ins8(best, x);
        }
#pragma unroll
        for (int j = 0; j < 8; ++j)
            idxo[(long)q * 8 + j] = (int)(best[j] & 0xFFFFFFFFu);
        return;
    }

    // ================= GEMM block (1536 total) ============================
    const int id = blockIdx.x - 64;
    const int bx = id % 12;
    const int by = id / 12;

    const int lane = tid & 63;
    const int wv   = tid >> 6;
    const int quad = lane >> 4;
    const int l15  = lane & 15;
    const int m0 = by * 128;
    const int n0 = bx * 128;
    const int mh = (wv & 1) * 64, nh = (wv >> 1) * 64;

    const int srow  = tid >> 1;
    const int shalf = (tid & 1) * 16;
    const int Kd = 256;

    float4v acc[4][4];
#pragma unroll
    for (int i = 0; i < 4; ++i)
#pragma unroll
        for (int j = 0; j < 4; ++j) acc[i][j] = (float4v)(0.f);

    for (int k0 = 0; k0 < Kd; k0 += 32) {
        const short8* asrc = (const short8*)(A + (long)(m0 + srow) * Kd + k0 + shalf);
        const short8* bsrc = (const short8*)(Bt + (long)(n0 + srow) * Kd + k0 + shalf);
        *(short8*)&As[srow][shalf]     = asrc[0];
        *(short8*)&As[srow][shalf + 8] = asrc[1];
        *(short8*)&Bs[srow][shalf]     = bsrc[0];
        *(short8*)&Bs[srow][shalf + 8] = bsrc[1];
        __syncthreads();

        short8 af[4], bfv[4];
#pragma unroll
        for (int i = 0; i < 4; ++i)
            af[i] = *(const short8*)&As[mh + i * 16 + l15][quad * 8];
#pragma unroll
        for (int j = 0; j < 4; ++j)
            bfv[j] = *(const short8*)&Bs[nh + j * 16 + l15][quad * 8];
#pragma unroll
        for (int i = 0; i < 4; ++i)
#pragma unroll
            for (int j = 0; j < 4; ++j)
                acc[i][j] = __builtin_amdgcn_mfma_f32_16x16x32_bf16(af[i], bfv[j], acc[i][j], 0, 0, 0);
        __syncthreads();
    }

    short* Cb;
    int stride, cb;
    if (n0 < 512) { Cb = qall;  stride = 512;  cb = n0; }
    else          { Cb = kvall; stride = 1024; cb = n0 - 512; }

#pragma unroll
    for (int i = 0; i < 4; ++i)
#pragma unroll
        for (int j = 0; j < 4; ++j) {
            const int col = cb + nh + j * 16 + l15;
#pragma unroll
            for (int r = 0; r < 4; ++r) {
                const int row = m0 + mh + i * 16 + quad * 4 + r;
                Cb[(long)row * stride + col] = f2bf(acc[i][j][r]);
            }
        }
}

// ---------------------------------------------------------------------------
// Dispatch 3: scatter -- builds rowmap[sorted] = original global group index.
// Only an index permutation; no point/feature data is moved (r12 lesson).
// ---------------------------------------------------------------------------
__global__ __launch_bounds__(256) void scatter_kernel(const unsigned short* __restrict__ cid,
                                                      const u32* __restrict__ cellStart,
                                                      u32* __restrict__ cellOff,
                                                      int* __restrict__ rowmap)
{
    const int i = blockIdx.x * 256 + threadIdx.x;    // original global 0..16383
    const int b = i >> 13;
    const int c = cid[i];
    const u32 dst = cellStart[b * (NCELLS + 1) + c] + atomicAdd(&cellOff[b * NCELLS + c], 1u);
    rowmap[b * N_PTS + dst] = i;
}

// ---------------------------------------------------------------------------
// Dispatch 4: fused KNN attention -- identical math/addresses to r11, but
// queries are PROCESSED in Morton order (g = order[sorted slot]) with an
// XCD-chunked block swizzle (4096 % 8 == 0, bijective). Spatially-adjacent
// queries share kv rows, so each XCD's L2 sees a small hot working set and
// the 8-row gathers hit cache. Outputs bit-identical (order-only change).
// ---------------------------------------------------------------------------
__global__ __launch_bounds__(256) void attn_kernel(const short* qall,
                                                   const short* __restrict__ kvall,
                                                   const int* __restrict__ idxp,
                                                   const int* __restrict__ order,
                                                   short* outp)
{
    __shared__ float attn_s[4][8][8];
    const int wave = threadIdx.x >> 6;
    const int lane = threadIdx.x & 63;
    // XCD-chunked swizzle: XCD k processes sorted blocks [k*512, (k+1)*512)
    const int sbid = ((blockIdx.x & 7) << 9) | (blockIdx.x >> 3);
    const int g = order[sbid * 4 + wave];            // original global group
    const int b = g >> 13;
    const int* myidx = idxp + (long)g * 8;

    {
        const int h = lane >> 3;
        const int k = lane & 7;
        const int j = myidx[k];
        const short8* qrow = (const short8*)(qall + (long)g * 512 + h * 64);
        const short8* krow = (const short8*)(kvall + ((long)(b * N_PTS + j)) * 1024 + h * 64);

        float dot = 0.f;
#pragma unroll
        for (int c = 0; c < 8; ++c) {
            const short8 qv = qrow[c];
            const short8 kv = krow[c];
#pragma unroll
            for (int e = 0; e < 8; ++e)
                dot = fmaf(bf2f(qv[e]), bf2f(kv[e]), dot);
        }
        dot *= 0.125f;

        float m = dot;
#pragma unroll
        for (int off = 1; off < 8; off <<= 1)
            m = fmaxf(m, __shfl_xor(m, off, 8));
        const float e = __expf(dot - m);
        float ssum = e;
#pragma unroll
        for (int off = 1; off < 8; off <<= 1)
            ssum += __shfl_xor(ssum, off, 8);
        attn_s[wave][h][k] = e / ssum;
    }
    __syncthreads();                      // drains q reads before aliased writes

    const int d8 = lane * 8;
    const int h2 = lane >> 3;
    float o[8] = {0.f, 0.f, 0.f, 0.f, 0.f, 0.f, 0.f, 0.f};
#pragma unroll
    for (int kk = 0; kk < 8; ++kk) {
        const int jj = myidx[kk];
        const float w = attn_s[wave][h2][kk];
        const short8 v = *(const short8*)(kvall + ((long)(b * N_PTS + jj)) * 1024 + 512 + d8);
#pragma unroll
        for (int e = 0; e < 8; ++e)
            o[e] = fmaf(w, bf2f(v[e]), o[e]);
    }
    short8 ov = {f2bf(o[0]), f2bf(o[1]), f2bf(o[2]), f2bf(o[3]),
                 f2bf(o[4]), f2bf(o[5]), f2bf(o[6]), f2bf(o[7])};
    *(short8*)(outp + (long)g * 512 + d8) = ov;
}

// ---------------------------------------------------------------------------
// Out-projection bf16 MFMA GEMM: C f32 = A[M,512] x Bt[256,512]^T + bias.
// (unchanged r11 staging -- r14 lesson)
// ---------------------------------------------------------------------------
__global__ __launch_bounds__(256) void gemm_out(const short* __restrict__ A,
                                                const short* __restrict__ Bt,
                                                const float* __restrict__ bias,
                                                float* __restrict__ C,
                                                int N, int Kd)
{
    __shared__ short As[128][40];
    __shared__ short Bs[128][40];

    const int tid  = threadIdx.x;
    const int lane = tid & 63;
    const int wv   = tid >> 6;
    const int quad = lane >> 4;
    const int l15  = lane & 15;
    const int m0 = blockIdx.y * 128;
    const int n0 = blockIdx.x * 128;
    const int mh = (wv & 1) * 64, nh = (wv >> 1) * 64;

    const int srow  = tid >> 1;
    const int shalf = (tid & 1) * 16;

    float4v acc[4][4];
#pragma unroll
    for (int i = 0; i < 4; ++i)
#pragma unroll
        for (int j = 0; j < 4; ++j) acc[i][j] = (float4v)(0.f);

    for (int k0 = 0; k0 < Kd; k0 += 32) {
        const short8* asrc = (const short8*)(A + (long)(m0 + srow) * Kd + k0 + shalf);
        const short8* bsrc = (const short8*)(Bt + (long)(n0 + srow) * Kd + k0 + shalf);
        *(short8*)&As[srow][shalf]     = asrc[0];
        *(short8*)&As[srow][shalf + 8] = asrc[1];
        *(short8*)&Bs[srow][shalf]     = bsrc[0];
        *(short8*)&Bs[srow][shalf + 8] = bsrc[1];
        __syncthreads();

        short8 af[4], bfv[4];
#pragma unroll
        for (int i = 0; i < 4; ++i)
            af[i] = *(const short8*)&As[mh + i * 16 + l15][quad * 8];
#pragma unroll
        for (int j = 0; j < 4; ++j)
            bfv[j] = *(const short8*)&Bs[nh + j * 16 + l15][quad * 8];
#pragma unroll
        for (int i = 0; i < 4; ++i)
#pragma unroll
            for (int j = 0; j < 4; ++j)
                acc[i][j] = __builtin_amdgcn_mfma_f32_16x16x32_bf16(af[i], bfv[j], acc[i][j], 0, 0, 0);
        __syncthreads();
    }

#pragma unroll
    for (int i = 0; i < 4; ++i)
#pragma unroll
        for (int j = 0; j < 4; ++j) {
            const int col = n0 + nh + j * 16 + l15;
            const float bb = bias[col];
#pragma unroll
            for (int r = 0; r < 4; ++r) {
                const int row = m0 + mh + i * 16 + quad * 4 + r;
                C[(long)row * N + col] = acc[i][j][r] + bb;
            }
        }
}

// ---------------------------------------------------------------------------
extern "C" void kernel_launch(void* const* d_in, const int* in_sizes, int n_in,
                              void* d_out, int out_size, void* d_ws, size_t ws_size,
                              hipStream_t stream)
{
    const float* x    = (const float*)d_in[0];  // [2,8192,256]
    const float* pos  = (const float*)d_in[1];  // [2,8192,3]
    const float* Wq   = (const float*)d_in[2];  // [256,512]
    const float* Wkv  = (const float*)d_in[3];  // [256,1024]
    const float* Wout = (const float*)d_in[4];  // [512,256]
    const float* bout = (const float*)d_in[5];  // [256]
    float* out = (float*)d_out;                 // [2,8192,256] f32

    const int M = 16384;

    // workspace layout:
    char* ws = (char*)d_ws;
    int*   idxp  = (int*)ws;                          ws += 1 << 19;             // 512 KB
    short* qall  = (short*)ws;                        ws += (long)M * 512 * 2;   // 16 MB
    short* kvall = (short*)ws;                        ws += (long)M * 1024 * 2;  // 32 MB
    short* xb    = (short*)ws;                        ws += (long)M * 256 * 2;   // 8 MB
    short* wqkvt = (short*)ws;                        ws += 1536 * 256 * 2;      // 768 KB
    short* woutt = (short*)ws;                        ws += 256 * 512 * 2;       // 256 KB
    u64*  partial = (u64*)ws;                         ws += (long)128 * 16384 * 8; // 16 MB
    u32*  cellCount = (u32*)ws;                       ws += 2L * NCELLS * 4;     // 256 KB
    u32*  cellOff   = (u32*)ws;                       ws += 2L * NCELLS * 4;     // 256 KB (contiguous w/ cellCount)
    u32*  cellStart = (u32*)ws;                       ws += 2L * (NCELLS + 1) * 4 + 56;
    unsigned short* cid = (unsigned short*)ws;        ws += (long)M * 2;         // 32 KB
    int*   rowmap = (int*)ws;                         ws += (long)M * 4;         // 64 KB

    hipMemsetAsync(cellCount, 0, 4L * NCELLS * 4, stream);   // count + off

    fused_knn_conv<<<5184, 256, 0, stream>>>(pos, partial, x, Wq, Wkv, Wout,
                                             xb, wqkvt, woutt, cellCount, cid);
    fused_gemm_merge<<<1602, 256, 0, stream>>>(xb, wqkvt, qall, kvall, partial,
                                               idxp, cellCount, cellStart);
    scatter_kernel<<<64, 256, 0, stream>>>(cid, cellStart, cellOff, rowmap);
    attn_kernel<<<M / 4, 256, 0, stream>>>(qall, kvall, idxp, rowmap, qall);  // in-place
    gemm_out<<<dim3(2, 128), 256, 0, stream>>>(qall, woutt, bout, out, 256, 512);
}